// Round 1
// baseline (453.439 us; speedup 1.0000x reference)
//
#include <hip/hip_runtime.h>
#include <math.h>

#define N_IMG 32
#define N_ATOM 400000
#define NE (N_ATOM*3)        // 1,200,000 floats per image row
#define NE4 (NE/4)           // 300,000 float4 per image row
#define KMAXC 0.1f
#define DLTKC 0.02f
#define EPSE 0.1f

// ws float layout:
// [0..30]    Sdd per link (31)
// [31..60]   Spm per interior image (30)
// [61..90]   Sfp (30)
// [91..120]  Sfm (30)
// [121..150] Sff (30)
// [160..249] coeffs A[30], B[30], C[30]
#define OFF_SDD 0
#define OFF_SPM 31
#define OFF_SFP 61
#define OFF_SFM 91
#define OFF_SFF 121
#define NSUM 151
#define OFF_CO 160

__device__ __forceinline__ float dot4(float4 a, float4 b) {
    return a.x*b.x + a.y*b.y + a.z*b.z + a.w*b.w;
}
__device__ __forceinline__ float4 sub4(float4 a, float4 b) {
    return make_float4(a.x-b.x, a.y-b.y, a.z-b.z, a.w-b.w);
}
__device__ __forceinline__ float wred64(float v) {
#pragma unroll
    for (int m = 32; m >= 1; m >>= 1) v += __shfl_xor(v, m, 64);
    return v;
}

__global__ __launch_bounds__(256) void eb_pass1(const float* __restrict__ pos,
                                                const float* __restrict__ frc,
                                                float* __restrict__ sums) {
    __shared__ float ls[NSUM];
    for (int i = threadIdx.x; i < NSUM; i += 256) ls[i] = 0.f;
    __syncthreads();

    const int t = blockIdx.x * 256 + threadIdx.x;   // float4 column index
    const bool act = t < NE4;
    const float4* pos4 = reinterpret_cast<const float4*>(pos);
    const float4* frc4 = reinterpret_cast<const float4*>(frc);
    const float4 z4 = make_float4(0.f, 0.f, 0.f, 0.f);
    const int lane = threadIdx.x & 63;

    float4 p_prev = act ? pos4[t] : z4;
    float4 d_prev = z4;
#pragma unroll 1
    for (int r = 1; r < N_IMG; ++r) {
        float4 p = act ? pos4[(size_t)r * NE4 + t] : z4;
        float4 d = sub4(p, p_prev);
        float sdd = wred64(dot4(d, d));
        if (lane == 0) atomicAdd(&ls[OFF_SDD + (r - 1)], sdd);
        if (r >= 2) {
            float4 f = act ? frc4[(size_t)(r - 1) * NE4 + t] : z4;
            float spm = wred64(dot4(d_prev, d));
            float sfp = wred64(dot4(f, d_prev));
            float sfm = wred64(dot4(f, d));
            float sff = wred64(dot4(f, f));
            if (lane == 0) {
                int jj = r - 2;
                atomicAdd(&ls[OFF_SPM + jj], spm);
                atomicAdd(&ls[OFF_SFP + jj], sfp);
                atomicAdd(&ls[OFF_SFM + jj], sfm);
                atomicAdd(&ls[OFF_SFF + jj], sff);
            }
        }
        p_prev = p;
        d_prev = d;
    }
    __syncthreads();
    for (int i = threadIdx.x; i < NSUM; i += 256) atomicAdd(&sums[i], ls[i]);
}

__global__ void eb_coeff(const float* __restrict__ eng,
                         const float* __restrict__ sums,
                         float* __restrict__ co) {
    if (threadIdx.x != 0 || blockIdx.x != 0) return;
    float e[N_IMG];
    float emin = 1e30f, emax = -1e30f;
    int imax = 0;
    for (int i = 0; i < N_IMG; ++i) {
        float v = eng[i];
        e[i] = v;
        if (v < emin) emin = v;
        if (v > emax) { emax = v; imax = i; }   // strict > -> first max, matches argmax
    }
    const float eref = emin - EPSE;
    float k[N_IMG - 1];
    for (int l = 0; l < N_IMG - 1; ++l) {
        float ei = fmaxf(e[l + 1], e[l]);
        float kk = KMAXC - DLTKC * (emax - ei) / (emax - eref);
        if (ei < eref) kk = KMAXC - DLTKC;
        k[l] = kk;
    }
    for (int jj = 0; jj < N_IMG - 2; ++jj) {
        float e0 = e[jj], e1 = e[jj + 1], e2 = e[jj + 2];
        float km = k[jj], kp = k[jj + 1];
        float pp = (e2 > e1 && e1 > e0) ? 1.f : 0.f;
        float mm = (e2 < e1 && e1 < e0) ? 1.f : 0.f;
        float nb = 1.f - fmaxf(pp, mm);
        float mp = ((e2 > e1) ? 1.f : 0.f) * nb;
        float mq = ((e2 < e1) ? 1.f : 0.f) * nb;
        float dvmax = fmaxf(fabsf(e2 - e1), fabsf(e0 - e1));
        float dvmin = fminf(fabsf(e2 - e1), fabsf(e0 - e1));
        float a = pp + dvmax * mp + dvmin * mq;   // coeff of tau_p
        float b = mm + dvmin * mp + dvmax * mq;   // coeff of tau_m
        float Spp = sums[OFF_SDD + jj];
        float Smm = sums[OFF_SDD + jj + 1];
        float Spm = sums[OFF_SPM + jj];
        float Sfp = sums[OFF_SFP + jj];
        float Sfm = sums[OFF_SFM + jj];
        float Sff = sums[OFF_SFF + jj];
        float ntau2 = a * a * Spp + 2.f * a * b * Spm + b * b * Smm;
        float ntau = sqrtf(ntau2);
        float ta = a / ntau, tb = b / ntau;
        float fpar = ta * Sfp + tb * Sfm;                       // dot(frc, tau)
        float spar = kp * sqrtf(Smm) - km * sqrtf(Spp);         // spr_para magnitude
        float ffpp = Sff - fpar * fpar;                         // |frc_perp|^2
        float strau = ta * (kp * Spm - km * Spp) + tb * (kp * Smm - km * Spm); // dot(spr,tau)
        float Sss = kp * kp * Smm - 2.f * kp * km * Spm + km * km * Spp;       // dot(spr,spr)
        float sspp = Sss - 2.f * spar * strau + spar * spar;    // |spr_perp|^2
        float Ssf = kp * Sfm - km * Sfp;                        // dot(spr,frc)
        float spfp = Ssf - fpar * strau;                        // dot(spr_perp,frc_perp)
        float sw = (2.0f / 3.14159265358979323846f) * atan2f(ffpp, sspp);
        float c = spfp * sw;
        float g = (jj == imax) ? 2.f : 1.f;                     // .at[i_raw].multiply(2.0)
        float w = (c - g) * fpar / ntau;
        co[jj]      = 1.f - c;        // A: coeff of frc
        co[30 + jj] = kp + w * b;     // B: coeff of tau_m (=d[j])
        co[60 + jj] = w * a - km;     // C: coeff of tau_p (=d[j-1])
    }
}

__global__ __launch_bounds__(256) void eb_pass2(const float* __restrict__ pos,
                                                const float* __restrict__ frc,
                                                const float* __restrict__ co,
                                                float* __restrict__ out) {
    __shared__ float A[30], B[30], C[30];
    if (threadIdx.x < 30) {
        A[threadIdx.x] = co[threadIdx.x];
        B[threadIdx.x] = co[30 + threadIdx.x];
        C[threadIdx.x] = co[60 + threadIdx.x];
    }
    __syncthreads();
    const int t = blockIdx.x * 256 + threadIdx.x;
    if (t >= NE4) return;
    const float4* pos4 = reinterpret_cast<const float4*>(pos);
    const float4* frc4 = reinterpret_cast<const float4*>(frc);
    float4* out4 = reinterpret_cast<float4*>(out);

    // Reverse sweep over image rows (tail of pass1's reads may still be in L3).
    size_t i31 = (size_t)31 * NE4 + t;
    float4 p_next = pos4[i31];
    out4[i31] = frc4[i31];
    float4 p30 = pos4[(size_t)30 * NE4 + t];
    float4 d_next = sub4(p_next, p30);   // d[30]
    p_next = p30;
#pragma unroll 1
    for (int l = 29; l >= 0; --l) {
        float4 p = pos4[(size_t)l * NE4 + t];
        float4 d = sub4(p_next, p);               // d[l] = tau_p of image l+1
        float4 f = frc4[(size_t)(l + 1) * NE4 + t];
        float ca = A[l], cb = B[l], cc = C[l];
        float4 o;
        o.x = ca * f.x + cb * d_next.x + cc * d.x;
        o.y = ca * f.y + cb * d_next.y + cc * d.y;
        o.z = ca * f.z + cb * d_next.z + cc * d.z;
        o.w = ca * f.w + cb * d_next.w + cc * d.w;
        out4[(size_t)(l + 1) * NE4 + t] = o;
        d_next = d;
        p_next = p;
    }
    out4[t] = frc4[t];
}

extern "C" void kernel_launch(void* const* d_in, const int* in_sizes, int n_in,
                              void* d_out, int out_size, void* d_ws, size_t ws_size,
                              hipStream_t stream) {
    const float* pos = (const float*)d_in[0];
    const float* frc = (const float*)d_in[1];
    const float* eng = (const float*)d_in[2];
    float* out = (float*)d_out;
    float* ws = (float*)d_ws;

    hipMemsetAsync(d_ws, 0, NSUM * sizeof(float), stream);
    const int blocks = (NE4 + 255) / 256;
    eb_pass1<<<blocks, 256, 0, stream>>>(pos, frc, ws);
    eb_coeff<<<1, 64, 0, stream>>>(eng, ws, ws + OFF_CO);
    eb_pass2<<<blocks, 256, 0, stream>>>(pos, frc, ws + OFF_CO, out);
}

// Round 2
// 440.303 us; speedup vs baseline: 1.0298x; 1.0298x over previous
//
#include <hip/hip_runtime.h>
#include <math.h>

#define N_IMG 32
#define N_ATOM 400000
#define NE (N_ATOM*3)        // 1,200,000 floats per image row
#define NE4 (NE/4)           // 300,000 float4 per image row
#define KMAXC 0.1f
#define DLTKC 0.02f
#define EPSE 0.1f

// ws float layout:
// [0..30]    Sdd per link (31)
// [31..60]   Spm per interior image (30)
// [61..90]   Sfp (30)
// [91..120]  Sfm (30)
// [121..150] Sff (30)
// [160..249] coeffs A[30], B[30], C[30]
#define OFF_SDD 0
#define OFF_SPM 31
#define OFF_SFP 61
#define OFF_SFM 91
#define OFF_SFF 121
#define NSUM 151
#define OFF_CO 160

__device__ __forceinline__ float dot4(float4 a, float4 b) {
    return a.x*b.x + a.y*b.y + a.z*b.z + a.w*b.w;
}
__device__ __forceinline__ float4 sub4(float4 a, float4 b) {
    return make_float4(a.x-b.x, a.y-b.y, a.z-b.z, a.w-b.w);
}

// Full-wave (64-lane) sum via DPP on the VALU pipe (no DS ops).
// rocPRIM-style GFX9 sequence: row_shr 1/2/4/8, row_bcast:15 (rows 1,3),
// row_bcast:31 (rows 2,3). Lane 63 ends with the total.
__device__ __forceinline__ float wred_dpp(float x) {
    x += __int_as_float(__builtin_amdgcn_update_dpp(0, __float_as_int(x), 0x111, 0xf, 0xf, false)); // row_shr:1
    x += __int_as_float(__builtin_amdgcn_update_dpp(0, __float_as_int(x), 0x112, 0xf, 0xf, false)); // row_shr:2
    x += __int_as_float(__builtin_amdgcn_update_dpp(0, __float_as_int(x), 0x114, 0xf, 0xf, false)); // row_shr:4
    x += __int_as_float(__builtin_amdgcn_update_dpp(0, __float_as_int(x), 0x118, 0xf, 0xf, false)); // row_shr:8
    x += __int_as_float(__builtin_amdgcn_update_dpp(0, __float_as_int(x), 0x142, 0xa, 0xf, false)); // row_bcast:15
    x += __int_as_float(__builtin_amdgcn_update_dpp(0, __float_as_int(x), 0x143, 0xc, 0xf, false)); // row_bcast:31
    return x;   // valid in lane 63
}

__global__ __launch_bounds__(256) void eb_pass1(const float* __restrict__ pos,
                                                const float* __restrict__ frc,
                                                float* __restrict__ sums) {
    __shared__ float ls[NSUM];
    for (int i = threadIdx.x; i < NSUM; i += 256) ls[i] = 0.f;
    __syncthreads();

    const int t = blockIdx.x * 256 + threadIdx.x;   // float4 column index
    const bool act = t < NE4;
    const float4* pos4 = reinterpret_cast<const float4*>(pos);
    const float4* frc4 = reinterpret_cast<const float4*>(frc);
    const float4 z4 = make_float4(0.f, 0.f, 0.f, 0.f);
    const int lane = threadIdx.x & 63;

    // Peel rows 0,1: link 0 (Sdd[0]) has no interior-image sums.
    float4 p0 = act ? pos4[t] : z4;
    float4 p1 = act ? pos4[(size_t)NE4 + t] : z4;
    float4 d_prev = sub4(p1, p0);   // d[0]
    {
        float sdd = wred_dpp(dot4(d_prev, d_prev));
        if (lane == 63) atomicAdd(&ls[OFF_SDD + 0], sdd);
    }
    float4 p_prev = p1;

#pragma unroll 5
    for (int r = 2; r < N_IMG; ++r) {          // 30 iterations
        float4 p = act ? pos4[(size_t)r * NE4 + t] : z4;
        float4 f = act ? frc4[(size_t)(r - 1) * NE4 + t] : z4;
        float4 d = sub4(p, p_prev);
        float sdd = wred_dpp(dot4(d, d));
        float spm = wred_dpp(dot4(d_prev, d));
        float sfp = wred_dpp(dot4(f, d_prev));
        float sfm = wred_dpp(dot4(f, d));
        float sff = wred_dpp(dot4(f, f));
        if (lane == 63) {
            int jj = r - 2;
            atomicAdd(&ls[OFF_SDD + (r - 1)], sdd);
            atomicAdd(&ls[OFF_SPM + jj], spm);
            atomicAdd(&ls[OFF_SFP + jj], sfp);
            atomicAdd(&ls[OFF_SFM + jj], sfm);
            atomicAdd(&ls[OFF_SFF + jj], sff);
        }
        p_prev = p;
        d_prev = d;
    }
    __syncthreads();
    for (int i = threadIdx.x; i < NSUM; i += 256) atomicAdd(&sums[i], ls[i]);
}

__global__ void eb_coeff(const float* __restrict__ eng,
                         const float* __restrict__ sums,
                         float* __restrict__ co) {
    const int jj = threadIdx.x;        // one interior image per thread
    if (jj >= N_IMG - 2 || blockIdx.x != 0) return;
    float e[N_IMG];
    float emin = 1e30f, emax = -1e30f;
    int imax = 0;
    for (int i = 0; i < N_IMG; ++i) {
        float v = eng[i];
        e[i] = v;
        if (v < emin) emin = v;
        if (v > emax) { emax = v; imax = i; }   // strict > -> first max, matches argmax
    }
    const float eref = emin - EPSE;
    float e0 = e[jj], e1 = e[jj + 1], e2 = e[jj + 2];
    // k for the two links of this image
    float eim = fmaxf(e1, e0);
    float km = KMAXC - DLTKC * (emax - eim) / (emax - eref);
    if (eim < eref) km = KMAXC - DLTKC;
    float eip = fmaxf(e2, e1);
    float kp = KMAXC - DLTKC * (emax - eip) / (emax - eref);
    if (eip < eref) kp = KMAXC - DLTKC;

    float pp = (e2 > e1 && e1 > e0) ? 1.f : 0.f;
    float mm = (e2 < e1 && e1 < e0) ? 1.f : 0.f;
    float nb = 1.f - fmaxf(pp, mm);
    float mp = ((e2 > e1) ? 1.f : 0.f) * nb;
    float mq = ((e2 < e1) ? 1.f : 0.f) * nb;
    float dvmax = fmaxf(fabsf(e2 - e1), fabsf(e0 - e1));
    float dvmin = fminf(fabsf(e2 - e1), fabsf(e0 - e1));
    float a = pp + dvmax * mp + dvmin * mq;   // coeff of tau_p
    float b = mm + dvmin * mp + dvmax * mq;   // coeff of tau_m
    float Spp = sums[OFF_SDD + jj];
    float Smm = sums[OFF_SDD + jj + 1];
    float Spm = sums[OFF_SPM + jj];
    float Sfp = sums[OFF_SFP + jj];
    float Sfm = sums[OFF_SFM + jj];
    float Sff = sums[OFF_SFF + jj];
    float ntau2 = a * a * Spp + 2.f * a * b * Spm + b * b * Smm;
    float ntau = sqrtf(ntau2);
    float ta = a / ntau, tb = b / ntau;
    float fpar = ta * Sfp + tb * Sfm;                       // dot(frc, tau)
    float spar = kp * sqrtf(Smm) - km * sqrtf(Spp);         // spr_para magnitude
    float ffpp = Sff - fpar * fpar;                         // |frc_perp|^2
    float strau = ta * (kp * Spm - km * Spp) + tb * (kp * Smm - km * Spm); // dot(spr,tau)
    float Sss = kp * kp * Smm - 2.f * kp * km * Spm + km * km * Spp;       // dot(spr,spr)
    float sspp = Sss - 2.f * spar * strau + spar * spar;    // |spr_perp|^2
    float Ssf = kp * Sfm - km * Sfp;                        // dot(spr,frc)
    float spfp = Ssf - fpar * strau;                        // dot(spr_perp,frc_perp)
    float sw = (2.0f / 3.14159265358979323846f) * atan2f(ffpp, sspp);
    float c = spfp * sw;
    float g = (jj == imax) ? 2.f : 1.f;                     // .at[i_raw].multiply(2.0)
    float w = (c - g) * fpar / ntau;
    co[jj]      = 1.f - c;        // A: coeff of frc
    co[30 + jj] = kp + w * b;     // B: coeff of tau_m (=d[j])
    co[60 + jj] = w * a - km;     // C: coeff of tau_p (=d[j-1])
}

__global__ __launch_bounds__(256) void eb_pass2(const float* __restrict__ pos,
                                                const float* __restrict__ frc,
                                                const float* __restrict__ co,
                                                float* __restrict__ out) {
    __shared__ float A[30], B[30], C[30];
    if (threadIdx.x < 30) {
        A[threadIdx.x] = co[threadIdx.x];
        B[threadIdx.x] = co[30 + threadIdx.x];
        C[threadIdx.x] = co[60 + threadIdx.x];
    }
    __syncthreads();
    const int t = blockIdx.x * 256 + threadIdx.x;
    if (t >= NE4) return;
    const float4* pos4 = reinterpret_cast<const float4*>(pos);
    const float4* frc4 = reinterpret_cast<const float4*>(frc);
    float4* out4 = reinterpret_cast<float4*>(out);

    // Reverse sweep over image rows (tail of pass1's reads is hottest in L3).
    size_t i31 = (size_t)31 * NE4 + t;
    float4 p_next = pos4[i31];
    out4[i31] = frc4[i31];
    float4 p30 = pos4[(size_t)30 * NE4 + t];
    float4 d_next = sub4(p_next, p30);   // d[30]
    p_next = p30;
#pragma unroll 5
    for (int l = 29; l >= 0; --l) {      // 30 iterations
        float4 p = pos4[(size_t)l * NE4 + t];
        float4 d = sub4(p_next, p);               // d[l] = tau_p of image l+1
        float4 f = frc4[(size_t)(l + 1) * NE4 + t];
        float ca = A[l], cb = B[l], cc = C[l];
        float4 o;
        o.x = ca * f.x + cb * d_next.x + cc * d.x;
        o.y = ca * f.y + cb * d_next.y + cc * d.y;
        o.z = ca * f.z + cb * d_next.z + cc * d.z;
        o.w = ca * f.w + cb * d_next.w + cc * d.w;
        out4[(size_t)(l + 1) * NE4 + t] = o;
        d_next = d;
        p_next = p;
    }
    out4[t] = frc4[t];
}

extern "C" void kernel_launch(void* const* d_in, const int* in_sizes, int n_in,
                              void* d_out, int out_size, void* d_ws, size_t ws_size,
                              hipStream_t stream) {
    const float* pos = (const float*)d_in[0];
    const float* frc = (const float*)d_in[1];
    const float* eng = (const float*)d_in[2];
    float* out = (float*)d_out;
    float* ws = (float*)d_ws;

    hipMemsetAsync(d_ws, 0, NSUM * sizeof(float), stream);
    const int blocks = (NE4 + 255) / 256;
    eb_pass1<<<blocks, 256, 0, stream>>>(pos, frc, ws);
    eb_coeff<<<1, 64, 0, stream>>>(eng, ws, ws + OFF_CO);
    eb_pass2<<<blocks, 256, 0, stream>>>(pos, frc, ws + OFF_CO, out);
}

// Round 3
// 421.601 us; speedup vs baseline: 1.0755x; 1.0444x over previous
//
#include <hip/hip_runtime.h>
#include <math.h>

#define N_IMG 32
#define N_ATOM 400000
#define NE (N_ATOM*3)        // 1,200,000 floats per image row
#define NE4 (NE/4)           // 300,000 float4 per image row
#define KMAXC 0.1f
#define DLTKC 0.02f
#define EPSE 0.1f

// global sums layout (ws floats [0..150]):
#define OFF_SDD 0    // 31 per-link |d|^2
#define OFF_SPM 31   // 30 d[j-1].d[j]
#define OFF_SFP 61   // 30 f[j].d[j-1]
#define OFF_SFM 91   // 30 f[j].d[j]
#define OFF_SFF 121  // 30 |f[j]|^2
#define NSUM 151
#define OFF_CO  160  // coeffs A[30],B[30],C[30] at ws[160..249]
#define OFF_PART 256 // per-block partials: NBXP rows x 160 floats
#define PSTRIDE 160

#define NBXP 586     // pass1 column-blocks (2 float4 cols per thread)
#define NBX2 1172    // pass2 column-blocks (1 float4 col per thread)
#define NCHUNK 5     // 5 chunks x 6 interior images = images 1..30

__device__ __forceinline__ float dot4(float4 a, float4 b) {
    return a.x*b.x + a.y*b.y + a.z*b.z + a.w*b.w;
}
__device__ __forceinline__ float4 sub4(float4 a, float4 b) {
    return make_float4(a.x-b.x, a.y-b.y, a.z-b.z, a.w-b.w);
}

// Full-wave (64-lane) sum via DPP on the VALU pipe. Lane 63 has the total.
__device__ __forceinline__ float wred_dpp(float x) {
    x += __int_as_float(__builtin_amdgcn_update_dpp(0, __float_as_int(x), 0x111, 0xf, 0xf, false)); // row_shr:1
    x += __int_as_float(__builtin_amdgcn_update_dpp(0, __float_as_int(x), 0x112, 0xf, 0xf, false)); // row_shr:2
    x += __int_as_float(__builtin_amdgcn_update_dpp(0, __float_as_int(x), 0x114, 0xf, 0xf, false)); // row_shr:4
    x += __int_as_float(__builtin_amdgcn_update_dpp(0, __float_as_int(x), 0x118, 0xf, 0xf, false)); // row_shr:8
    x += __int_as_float(__builtin_amdgcn_update_dpp(0, __float_as_int(x), 0x142, 0xa, 0xf, false)); // row_bcast:15
    x += __int_as_float(__builtin_amdgcn_update_dpp(0, __float_as_int(x), 0x143, 0xc, 0xf, false)); // row_bcast:31
    return x;
}

// grid: (NBXP, NCHUNK). Chunk c handles interior images j0..j0+5, j0 = 1+6c.
// Needs pos rows j0-1..j0+6 (8), frc rows j0..j0+5 (6). Computes diffs
// d[j0-1..j0+5] (7). Owns Sdd links j0-1..j0+4 (+link 30 for c==4) and the
// 4x6 per-image sums. Writes NON-ATOMIC partials to its own ws row.
__global__ __launch_bounds__(256) void eb_pass1(const float* __restrict__ pos,
                                                const float* __restrict__ frc,
                                                float* __restrict__ part) {
    const int c = blockIdx.y;
    const int j0 = 1 + 6 * c;
    const float4* pos4 = reinterpret_cast<const float4*>(pos);
    const float4* frc4 = reinterpret_cast<const float4*>(frc);

    float sdd[7], spm[6], sfp[6], sfm[6], sff[6];
#pragma unroll
    for (int i = 0; i < 7; ++i) sdd[i] = 0.f;
#pragma unroll
    for (int i = 0; i < 6; ++i) { spm[i] = 0.f; sfp[i] = 0.f; sfm[i] = 0.f; sff[i] = 0.f; }

    for (int t = blockIdx.x * 256 + threadIdx.x; t < NE4; t += 256 * NBXP) {
        float4 p_cur = pos4[(size_t)(j0 - 1) * NE4 + t];
        float4 p_nxt = pos4[(size_t)j0 * NE4 + t];
        float4 dprev = sub4(p_nxt, p_cur);          // d[j0-1]
        sdd[0] += dot4(dprev, dprev);
#pragma unroll
        for (int jj = 0; jj < 6; ++jj) {
            const int j = j0 + jj;
            float4 p2 = pos4[(size_t)(j + 1) * NE4 + t];
            float4 f  = frc4[(size_t)j * NE4 + t];
            float4 d  = sub4(p2, p_nxt);            // d[j]
            sdd[jj + 1] += dot4(d, d);
            spm[jj] += dot4(dprev, d);
            sfp[jj] += dot4(f, dprev);
            sfm[jj] += dot4(f, d);
            sff[jj] += dot4(f, f);
            dprev = d;
            p_nxt = p2;
        }
    }

    // pack into one array for the block reduction
    float v[31];
#pragma unroll
    for (int i = 0; i < 7; ++i) v[i] = sdd[i];
#pragma unroll
    for (int i = 0; i < 6; ++i) { v[7 + i] = spm[i]; v[13 + i] = sfp[i]; v[19 + i] = sfm[i]; v[25 + i] = sff[i]; }

    __shared__ float red[4][31];
    const int wave = threadIdx.x >> 6;
    const int lane = threadIdx.x & 63;
#pragma unroll
    for (int s = 0; s < 31; ++s) {
        float r = wred_dpp(v[s]);
        if (lane == 63) red[wave][s] = r;
    }
    __syncthreads();
    const int s = threadIdx.x;
    if (s < 31) {
        float r = red[0][s] + red[1][s] + red[2][s] + red[3][s];
        int slot; bool owned = true;
        if (s < 7)       { owned = (s < 6) || (c == NCHUNK - 1); slot = OFF_SDD + (j0 - 1) + s; }
        else if (s < 13) slot = OFF_SPM + (j0 - 1) + (s - 7);
        else if (s < 19) slot = OFF_SFP + (j0 - 1) + (s - 13);
        else if (s < 25) slot = OFF_SFM + (j0 - 1) + (s - 19);
        else             slot = OFF_SFF + (j0 - 1) + (s - 25);
        if (owned) part[(size_t)blockIdx.x * PSTRIDE + slot] = r;
    }
}

// grid: (NSUM, 1). Block b sums partials column b over NBXP rows -> sums[b].
__global__ __launch_bounds__(256) void eb_reduce(const float* __restrict__ part,
                                                 float* __restrict__ sums) {
    const int s = blockIdx.x;
    float acc = 0.f;
    for (int r = threadIdx.x; r < NBXP; r += 256)
        acc += part[(size_t)r * PSTRIDE + s];
    __shared__ float red[4];
    const int wave = threadIdx.x >> 6;
    const int lane = threadIdx.x & 63;
    float v = wred_dpp(acc);
    if (lane == 63) red[wave] = v;
    __syncthreads();
    if (threadIdx.x == 0) sums[s] = red[0] + red[1] + red[2] + red[3];
}

__global__ void eb_coeff(const float* __restrict__ eng,
                         const float* __restrict__ sums,
                         float* __restrict__ co) {
    const int jj = threadIdx.x;        // one interior image per thread
    if (jj >= N_IMG - 2 || blockIdx.x != 0) return;
    float e[N_IMG];
    float emin = 1e30f, emax = -1e30f;
    int imax = 0;
    for (int i = 0; i < N_IMG; ++i) {
        float v = eng[i];
        e[i] = v;
        if (v < emin) emin = v;
        if (v > emax) { emax = v; imax = i; }   // strict > -> first max = argmax
    }
    const float eref = emin - EPSE;
    float e0 = e[jj], e1 = e[jj + 1], e2 = e[jj + 2];
    float eim = fmaxf(e1, e0);
    float km = KMAXC - DLTKC * (emax - eim) / (emax - eref);
    if (eim < eref) km = KMAXC - DLTKC;
    float eip = fmaxf(e2, e1);
    float kp = KMAXC - DLTKC * (emax - eip) / (emax - eref);
    if (eip < eref) kp = KMAXC - DLTKC;

    float pp = (e2 > e1 && e1 > e0) ? 1.f : 0.f;
    float mm = (e2 < e1 && e1 < e0) ? 1.f : 0.f;
    float nb = 1.f - fmaxf(pp, mm);
    float mp = ((e2 > e1) ? 1.f : 0.f) * nb;
    float mq = ((e2 < e1) ? 1.f : 0.f) * nb;
    float dvmax = fmaxf(fabsf(e2 - e1), fabsf(e0 - e1));
    float dvmin = fminf(fabsf(e2 - e1), fabsf(e0 - e1));
    float a = pp + dvmax * mp + dvmin * mq;   // coeff of tau_p
    float b = mm + dvmin * mp + dvmax * mq;   // coeff of tau_m
    float Spp = sums[OFF_SDD + jj];
    float Smm = sums[OFF_SDD + jj + 1];
    float Spm = sums[OFF_SPM + jj];
    float Sfp = sums[OFF_SFP + jj];
    float Sfm = sums[OFF_SFM + jj];
    float Sff = sums[OFF_SFF + jj];
    float ntau2 = a * a * Spp + 2.f * a * b * Spm + b * b * Smm;
    float ntau = sqrtf(ntau2);
    float ta = a / ntau, tb = b / ntau;
    float fpar = ta * Sfp + tb * Sfm;                       // dot(frc, tau)
    float spar = kp * sqrtf(Smm) - km * sqrtf(Spp);         // spr_para magnitude
    float ffpp = Sff - fpar * fpar;                         // |frc_perp|^2
    float strau = ta * (kp * Spm - km * Spp) + tb * (kp * Smm - km * Spm); // dot(spr,tau)
    float Sss = kp * kp * Smm - 2.f * kp * km * Spm + km * km * Spp;       // dot(spr,spr)
    float sspp = Sss - 2.f * spar * strau + spar * spar;    // |spr_perp|^2
    float Ssf = kp * Sfm - km * Sfp;                        // dot(spr,frc)
    float spfp = Ssf - fpar * strau;                        // dot(spr_perp,frc_perp)
    float sw = (2.0f / 3.14159265358979323846f) * atan2f(ffpp, sspp);
    float cc = spfp * sw;
    float g = (jj == imax) ? 2.f : 1.f;                     // .at[i_raw].multiply(2.0)
    float w = (cc - g) * fpar / ntau;
    co[jj]      = 1.f - cc;       // A: coeff of frc
    co[30 + jj] = kp + w * b;     // B: coeff of tau_m (=d[j])
    co[60 + jj] = w * a - km;     // C: coeff of tau_p (=d[j-1])
}

// grid: (NBX2, NCHUNK). Chunk c writes out rows j0..j0+5.
__global__ __launch_bounds__(256) void eb_pass2(const float* __restrict__ pos,
                                                const float* __restrict__ frc,
                                                const float* __restrict__ co,
                                                float* __restrict__ out) {
    __shared__ float A[30], B[30], C[30];
    if (threadIdx.x < 30) {
        A[threadIdx.x] = co[threadIdx.x];
        B[threadIdx.x] = co[30 + threadIdx.x];
        C[threadIdx.x] = co[60 + threadIdx.x];
    }
    __syncthreads();
    const int t = blockIdx.x * 256 + threadIdx.x;
    if (t >= NE4) return;
    const int c = blockIdx.y;
    const int j0 = 1 + 6 * c;
    const float4* pos4 = reinterpret_cast<const float4*>(pos);
    const float4* frc4 = reinterpret_cast<const float4*>(frc);
    float4* out4 = reinterpret_cast<float4*>(out);

    if (c == 0) out4[t] = frc4[t];                                       // out[0]=frc[0]
    if (c == NCHUNK - 1) {
        size_t i31 = (size_t)31 * NE4 + t;
        out4[i31] = frc4[i31];                                           // out[31]=frc[31]
    }

    float4 p_cur = pos4[(size_t)(j0 - 1) * NE4 + t];
    float4 p_nxt = pos4[(size_t)j0 * NE4 + t];
    float4 dprev = sub4(p_nxt, p_cur);          // d[j0-1]
#pragma unroll
    for (int jj = 0; jj < 6; ++jj) {
        const int j = j0 + jj;
        float4 p2 = pos4[(size_t)(j + 1) * NE4 + t];
        float4 f  = frc4[(size_t)j * NE4 + t];
        float4 d  = sub4(p2, p_nxt);            // d[j]
        const int g = j - 1;
        float ca = A[g], cb = B[g], cd = C[g];
        float4 o;
        o.x = ca * f.x + cb * d.x + cd * dprev.x;
        o.y = ca * f.y + cb * d.y + cd * dprev.y;
        o.z = ca * f.z + cb * d.z + cd * dprev.z;
        o.w = ca * f.w + cb * d.w + cd * dprev.w;
        out4[(size_t)j * NE4 + t] = o;
        dprev = d;
        p_nxt = p2;
    }
}

extern "C" void kernel_launch(void* const* d_in, const int* in_sizes, int n_in,
                              void* d_out, int out_size, void* d_ws, size_t ws_size,
                              hipStream_t stream) {
    const float* pos = (const float*)d_in[0];
    const float* frc = (const float*)d_in[1];
    const float* eng = (const float*)d_in[2];
    float* out = (float*)d_out;
    float* ws = (float*)d_ws;
    float* sums = ws;                 // [0..150]
    float* co   = ws + OFF_CO;        // [160..249]
    float* part = ws + OFF_PART;      // NBXP x PSTRIDE

    eb_pass1<<<dim3(NBXP, NCHUNK), 256, 0, stream>>>(pos, frc, part);
    eb_reduce<<<NSUM, 256, 0, stream>>>(part, sums);
    eb_coeff<<<1, 64, 0, stream>>>(eng, sums, co);
    eb_pass2<<<dim3(NBX2, NCHUNK), 256, 0, stream>>>(pos, frc, co, out);
}